// Round 3
// baseline (1515.965 us; speedup 1.0000x reference)
//
#include <hip/hip_runtime.h>

// vector_attention: S=2048, B=32, D=256, H=4. fp32 accumulate everywhere.
// Dtype-adaptive: detect_k probes whether external tensors are bf16 or f32
// (device-side, graph-capture-safe) and all kernels branch on the ws flag.
// Intermediates in ws are always bf16. Manual LDS staging (no global_load_lds)
// this round to rule out staging as the NaN source.

typedef short  s16x8 __attribute__((ext_vector_type(8)));
typedef float  f32x4 __attribute__((ext_vector_type(4)));
typedef unsigned short u16;

struct alignas(8) U16x4 { u16 x, y, z, w; };

__device__ __forceinline__ float bu2f(u16 u) {
    union { unsigned int i; float f; } c; c.i = ((unsigned int)u) << 16; return c.f;
}
__device__ __forceinline__ float bs2f(short s) { return bu2f((u16)s); }
__device__ __forceinline__ u16 f2bu(float f) {  // round-to-nearest-even
    union { float f; unsigned int i; } c; c.f = f;
    unsigned int u = c.i;
    u += 0x7fffu + ((u >> 16) & 1u);
    return (u16)(u >> 16);
}

// ---------------------------------------------------------------------------
// Dtype probe: if q is bf16, the low u16 of each 32-bit word is a bf16 value
// ~N(0,1) whose exponent field lies in [96,141] (~100%). If q is f32, the low
// u16 is mantissa bits -> exponent field uniform -> ~18% in range.
// flag = 1 (bf16) / 0 (f32).
// ---------------------------------------------------------------------------
__global__ __launch_bounds__(256) void detect_k(const unsigned int* __restrict__ qw,
                                                int* __restrict__ flag)
{
    __shared__ int cnt[256];
    const int t = threadIdx.x;
    int c = 0;
    for (int i = 0; i < 1024; i++) {
        const unsigned int w = qw[t + i * 256];   // first 1 MB of q: safe either dtype
        const unsigned int e = (w >> 7) & 0xFFu;
        c += (e >= 96u && e <= 141u) ? 1 : 0;
    }
    cnt[t] = c;
    __syncthreads();
    for (int s = 128; s > 0; s >>= 1) {
        if (t < s) cnt[t] += cnt[t + s];
        __syncthreads();
    }
    if (t == 0) *flag = (cnt[0] > 131072) ? 1 : 0;   // 262144 samples, majority
}

// ---------------------------------------------------------------------------
// GEMM: C[M=65536,N=256] = op(A)[M,K=256] @ W[N=256,K]^T + bias[N], bf16 out.
// AMODE 0: A plain (external if aext: dtype per flag; else ws bf16).
// AMODE 1: a = relu((A-A2)*scale[k]+shift[k])   (A,A2 ws bf16).
// AMODE 2: a = relu(A*scale[k]+shift[k])        (A ws bf16).
// W/bias external: dtype per flag. Manual LDS staging.
// Tile 128x128, BK=32, 256 threads / 4 waves, wave = 64x64 (4x4 MFMA 16x16x32).
// ---------------------------------------------------------------------------
template<int AMODE>
__global__ __launch_bounds__(256) void gemm_k(
    const u16* __restrict__ A, const float* __restrict__ Af, const int aext,
    const u16* __restrict__ A2,
    const float* __restrict__ scale, const float* __restrict__ shift,
    const u16* __restrict__ W, const float* __restrict__ Wf,
    const u16* __restrict__ bias, const float* __restrict__ biasf,
    const int* __restrict__ dflag,
    u16* __restrict__ C)
{
    __shared__ __align__(16) u16 As[128 * 32];
    __shared__ __align__(16) u16 Bs[128 * 32];

    const int f32in = (*dflag == 0);

    const int tid   = threadIdx.x;
    const int tileN = blockIdx.x & 1;
    const int tileM = blockIdx.x >> 1;
    const int lane  = tid & 63;
    const int wave  = tid >> 6;
    const int wm    = wave & 1;
    const int wn    = wave >> 1;
    const int lrow  = lane & 15;
    const int quad  = lane >> 4;

    f32x4 acc[4][4];
#pragma unroll
    for (int i = 0; i < 4; i++)
#pragma unroll
        for (int j = 0; j < 4; j++) acc[i][j] = (f32x4){0.f, 0.f, 0.f, 0.f};

    const int  rA   = tid >> 2;        // 0..63 row within 64-row half
    const int  kq   = (tid & 3) << 3;  // 0,8,16,24
    const long rowA = (long)tileM * 128;
    const long rowB = (long)tileN * 128;

    for (int k0 = 0; k0 < 256; k0 += 32) {
        if (k0) __syncthreads();
#pragma unroll
        for (int j = 0; j < 2; j++) {
            const int  r   = j * 64 + rA;
            const long off = (rowA + r) * 256 + k0 + kq;
            u16* dstA = As + j * 2048 + tid * 8;

            if constexpr (AMODE == 0) {
                if (aext && f32in) {
                    const float* p = Af + off;
                    f32x4 a = *(const f32x4*)p;
                    f32x4 b = *(const f32x4*)(p + 4);
                    s16x8 o;
                    o[0] = (short)f2bu(a[0]); o[1] = (short)f2bu(a[1]);
                    o[2] = (short)f2bu(a[2]); o[3] = (short)f2bu(a[3]);
                    o[4] = (short)f2bu(b[0]); o[5] = (short)f2bu(b[1]);
                    o[6] = (short)f2bu(b[2]); o[7] = (short)f2bu(b[3]);
                    *(s16x8*)dstA = o;
                } else {
                    *(s16x8*)dstA = *(const s16x8*)(A + off);
                }
            } else {
                s16x8 xv = *(const s16x8*)(A + off);
                s16x8 yv;
                if constexpr (AMODE == 1) yv = *(const s16x8*)(A2 + off);
                s16x8 o;
#pragma unroll
                for (int e = 0; e < 8; e++) {
                    const int c = k0 + kq + e;
                    float x = bs2f(xv[e]);
                    if constexpr (AMODE == 1) x -= bs2f(yv[e]);
                    float a = fmaxf(fmaf(x, scale[c], shift[c]), 0.f);
                    o[e] = (short)f2bu(a);
                }
                *(s16x8*)dstA = o;
            }

            const long offW = (rowB + r) * 256 + k0 + kq;
            u16* dstB = Bs + j * 2048 + tid * 8;
            if (f32in) {
                const float* p = Wf + offW;
                f32x4 a = *(const f32x4*)p;
                f32x4 b = *(const f32x4*)(p + 4);
                s16x8 o;
                o[0] = (short)f2bu(a[0]); o[1] = (short)f2bu(a[1]);
                o[2] = (short)f2bu(a[2]); o[3] = (short)f2bu(a[3]);
                o[4] = (short)f2bu(b[0]); o[5] = (short)f2bu(b[1]);
                o[6] = (short)f2bu(b[2]); o[7] = (short)f2bu(b[3]);
                *(s16x8*)dstB = o;
            } else {
                *(s16x8*)dstB = *(const s16x8*)(W + offW);
            }
        }
        __syncthreads();

        s16x8 af[4], bf[4];
#pragma unroll
        for (int im = 0; im < 4; im++)
            af[im] = *(const s16x8*)(As + (wm * 64 + im * 16 + lrow) * 32 + quad * 8);
#pragma unroll
        for (int in = 0; in < 4; in++)
            bf[in] = *(const s16x8*)(Bs + (wn * 64 + in * 16 + lrow) * 32 + quad * 8);
#pragma unroll
        for (int im = 0; im < 4; im++)
#pragma unroll
            for (int in = 0; in < 4; in++)
                acc[im][in] = __builtin_amdgcn_mfma_f32_16x16x32_bf16(
                    af[im], bf[in], acc[im][in], 0, 0, 0);
    }

    // epilogue: C/D layout col=lane&15, row=quad*4+reg  [verified m89/m91]
#pragma unroll
    for (int in = 0; in < 4; in++) {
        const int col = (int)rowB + wn * 64 + in * 16 + lrow;
        const float bv = f32in ? biasf[col] : bu2f(bias[col]);
#pragma unroll
        for (int im = 0; im < 4; im++) {
            const long row0 = rowA + wm * 64 + im * 16 + quad * 4;
#pragma unroll
            for (int e = 0; e < 4; e++)
                C[(row0 + e) * 256 + col] = f2bu(acc[im][in][e] + bv);
        }
    }
}

// ---------------------------------------------------------------------------
// Per-channel sum/sumsq over 65536 rows x 256 channels (ws bf16 only).
// ---------------------------------------------------------------------------
template<bool DIFF>
__global__ __launch_bounds__(256) void stats_k(
    const u16* __restrict__ X, const u16* __restrict__ Y,
    float* __restrict__ sum, float* __restrict__ ss)
{
    __shared__ float rs[4 * 256];
    __shared__ float rq[4 * 256];
    const int t  = threadIdx.x;
    const int cg = (t & 63) * 4;
    const int rg = t >> 6;
    const long base = (long)blockIdx.x * 256;

    float s0 = 0, s1 = 0, s2 = 0, s3 = 0, q0 = 0, q1 = 0, q2 = 0, q3 = 0;
    for (int r = rg; r < 256; r += 4) {
        const long idx = (base + r) * 256 + cg;
        U16x4 xv = *(const U16x4*)(X + idx);
        float w0 = bu2f(xv.x), w1 = bu2f(xv.y), w2 = bu2f(xv.z), w3 = bu2f(xv.w);
        if (DIFF) {
            U16x4 yv = *(const U16x4*)(Y + idx);
            w0 -= bu2f(yv.x); w1 -= bu2f(yv.y); w2 -= bu2f(yv.z); w3 -= bu2f(yv.w);
        }
        s0 += w0; q0 += w0 * w0; s1 += w1; q1 += w1 * w1;
        s2 += w2; q2 += w2 * w2; s3 += w3; q3 += w3 * w3;
    }
    rs[rg * 256 + cg + 0] = s0; rq[rg * 256 + cg + 0] = q0;
    rs[rg * 256 + cg + 1] = s1; rq[rg * 256 + cg + 1] = q1;
    rs[rg * 256 + cg + 2] = s2; rq[rg * 256 + cg + 2] = q2;
    rs[rg * 256 + cg + 3] = s3; rq[rg * 256 + cg + 3] = q3;
    __syncthreads();
    float ts = rs[t] + rs[256 + t] + rs[512 + t] + rs[768 + t];
    float tq = rq[t] + rq[256 + t] + rq[512 + t] + rq[768 + t];
    atomicAdd(&sum[t], ts);
    atomicAdd(&ss[t], tq);
}

__global__ __launch_bounds__(256) void finalize_k(
    const float* __restrict__ sum, const float* __restrict__ ss,
    const u16* __restrict__ g, const float* __restrict__ gf,
    const u16* __restrict__ be, const float* __restrict__ bef,
    const int* __restrict__ dflag,
    float* __restrict__ scale, float* __restrict__ shift)
{
    const int f32in = (*dflag == 0);
    const int c = threadIdx.x;
    const float mean = sum[c] * (1.f / 65536.f);
    const float var  = ss[c] * (1.f / 65536.f) - mean * mean;
    const float rstd = rsqrtf(var + 1e-5f);
    const float gg = f32in ? gf[c] : bu2f(g[c]);
    const float bb = f32in ? bef[c] : bu2f(be[c]);
    const float sc = rstd * gg;
    scale[c] = sc;
    shift[c] = bb - mean * sc;
}

// ---------------------------------------------------------------------------
// Online softmax over S fused with weighted v-sum, chunked. (ws bf16 only)
// ---------------------------------------------------------------------------
__global__ __launch_bounds__(256) void softmax_chunk_k(
    const u16* __restrict__ L, const u16* __restrict__ V,
    float* __restrict__ pm, float* __restrict__ pl, float* __restrict__ pa)
{
    const int d = threadIdx.x, b = blockIdx.x, ch = blockIdx.y;
    float m = -3.0e38f, l = 0.f, acc = 0.f;
    const long base = ((long)ch * 128 * 32 + b) * 256 + d;
    for (int si = 0; si < 128; si++) {
        const long idx = base + (long)si * 32 * 256;
        const float x = bu2f(L[idx]);
        const float v = bu2f(V[idx]);
        const float mn = fmaxf(m, x);
        const float c  = __expf(m - mn);
        const float e  = __expf(x - mn);
        l   = l * c + e;
        acc = acc * c + e * v;
        m = mn;
    }
    const int p = (ch * 32 + b) * 256 + d;
    pm[p] = m; pl[p] = l; pa[p] = acc;
}

__global__ __launch_bounds__(256) void softmax_merge_k(
    const float* __restrict__ pm, const float* __restrict__ pl,
    const float* __restrict__ pa, float* __restrict__ xcat, int head)
{
    const int d = threadIdx.x, b = blockIdx.x;
    float M = -3.0e38f, L = 0.f, A = 0.f;
    for (int ch = 0; ch < 16; ch++) {
        const int p = (ch * 32 + b) * 256 + d;
        const float m = pm[p], l = pl[p], a = pa[p];
        const float mn = fmaxf(M, m);
        const float c1 = __expf(M - mn), c2 = __expf(m - mn);
        L = L * c1 + l * c2;
        A = A * c1 + a * c2;
        M = mn;
    }
    xcat[b * 1024 + head * 256 + d] = A / L;
}

// ---------------------------------------------------------------------------
// Final MLP: [32,1024] -> relu -> 256 -> relu -> 256. Weights external.
// ---------------------------------------------------------------------------
__global__ __launch_bounds__(256) void mlp_k(
    const float* __restrict__ xcat,
    const u16* __restrict__ mw0, const float* __restrict__ mw0f,
    const u16* __restrict__ mb0, const float* __restrict__ mb0f,
    const u16* __restrict__ mw1, const float* __restrict__ mw1f,
    const u16* __restrict__ mb1, const float* __restrict__ mb1f,
    const u16* __restrict__ mw2, const float* __restrict__ mw2f,
    const u16* __restrict__ mb2, const float* __restrict__ mb2f,
    const int* __restrict__ dflag,
    u16* __restrict__ out, float* __restrict__ outf)
{
    __shared__ float h0[1024];
    __shared__ float h1[256];
    __shared__ float h2[256];
    const int f32in = (*dflag == 0);
    const int j = threadIdx.x, b = blockIdx.x;
#pragma unroll
    for (int i = 0; i < 4; i++) h0[j + i * 256] = xcat[b * 1024 + j + i * 256];
    __syncthreads();

    float a0 = f32in ? mb0f[j] : bu2f(mb0[j]);
    if (f32in) {
        for (int k4 = 0; k4 < 256; k4++) {
            f32x4 wv = *(const f32x4*)(mw0f + j * 1024 + k4 * 4);
#pragma unroll
            for (int e = 0; e < 4; e++) a0 += h0[k4 * 4 + e] * wv[e];
        }
    } else {
        for (int k8 = 0; k8 < 128; k8++) {
            s16x8 wv = *(const s16x8*)(mw0 + j * 1024 + k8 * 8);
#pragma unroll
            for (int e = 0; e < 8; e++) a0 += h0[k8 * 8 + e] * bs2f(wv[e]);
        }
    }
    h1[j] = fmaxf(a0, 0.f);
    __syncthreads();

    float a1 = f32in ? mb1f[j] : bu2f(mb1[j]);
    if (f32in) {
        for (int k4 = 0; k4 < 64; k4++) {
            f32x4 wv = *(const f32x4*)(mw1f + j * 256 + k4 * 4);
#pragma unroll
            for (int e = 0; e < 4; e++) a1 += h1[k4 * 4 + e] * wv[e];
        }
    } else {
        for (int k8 = 0; k8 < 32; k8++) {
            s16x8 wv = *(const s16x8*)(mw1 + j * 256 + k8 * 8);
#pragma unroll
            for (int e = 0; e < 8; e++) a1 += h1[k8 * 8 + e] * bs2f(wv[e]);
        }
    }
    h2[j] = fmaxf(a1, 0.f);
    __syncthreads();

    float a2 = f32in ? mb2f[j] : bu2f(mb2[j]);
    if (f32in) {
        for (int k4 = 0; k4 < 64; k4++) {
            f32x4 wv = *(const f32x4*)(mw2f + j * 256 + k4 * 4);
#pragma unroll
            for (int e = 0; e < 4; e++) a2 += h2[k4 * 4 + e] * wv[e];
        }
    } else {
        for (int k8 = 0; k8 < 32; k8++) {
            s16x8 wv = *(const s16x8*)(mw2 + j * 256 + k8 * 8);
#pragma unroll
            for (int e = 0; e < 8; e++) a2 += h2[k8 * 8 + e] * bs2f(wv[e]);
        }
    }
    if (f32in) outf[b * 256 + j] = a2;
    else       out[b * 256 + j] = f2bu(a2);
}

// ---------------------------------------------------------------------------
extern "C" void kernel_launch(void* const* d_in, const int* in_sizes, int n_in,
                              void* d_out, int out_size, void* d_ws, size_t ws_size,
                              hipStream_t stream)
{
    // bf16 views
    const u16 *q16 = (const u16*)d_in[0], *k16 = (const u16*)d_in[1], *v16 = (const u16*)d_in[2];
    const u16 *wq16 = (const u16*)d_in[3], *bq16 = (const u16*)d_in[4];
    const u16 *wk16 = (const u16*)d_in[5], *bk16 = (const u16*)d_in[6];
    const u16 *wv16 = (const u16*)d_in[7], *bv16 = (const u16*)d_in[8];
    const u16 *g116 = (const u16*)d_in[9], *be116 = (const u16*)d_in[10];
    const u16 *wl116 = (const u16*)d_in[11], *bl116 = (const u16*)d_in[12];
    const u16 *g216 = (const u16*)d_in[13], *be216 = (const u16*)d_in[14];
    const u16 *wl216 = (const u16*)d_in[15], *bl216 = (const u16*)d_in[16];
    const u16 *mw016 = (const u16*)d_in[17], *mb016 = (const u16*)d_in[18];
    const u16 *mw116 = (const u16*)d_in[19], *mb116 = (const u16*)d_in[20];
    const u16 *mw216 = (const u16*)d_in[21], *mb216 = (const u16*)d_in[22];
    // f32 views (same addresses)
    const float *qf = (const float*)d_in[0], *kf = (const float*)d_in[1], *vf = (const float*)d_in[2];
    const float *wqf = (const float*)d_in[3], *bqf = (const float*)d_in[4];
    const float *wkf = (const float*)d_in[5], *bkf = (const float*)d_in[6];
    const float *wvf = (const float*)d_in[7], *bvf = (const float*)d_in[8];
    const float *g1f = (const float*)d_in[9], *be1f = (const float*)d_in[10];
    const float *wl1f = (const float*)d_in[11], *bl1f = (const float*)d_in[12];
    const float *g2f = (const float*)d_in[13], *be2f = (const float*)d_in[14];
    const float *wl2f = (const float*)d_in[15], *bl2f = (const float*)d_in[16];
    const float *mw0f = (const float*)d_in[17], *mb0f = (const float*)d_in[18];
    const float *mw1f = (const float*)d_in[19], *mb1f = (const float*)d_in[20];
    const float *mw2f = (const float*)d_in[21], *mb2f = (const float*)d_in[22];

    const size_t TEN = 33554432ull;         // one [65536,256] bf16 tensor
    const size_t BUF_OFF = 2097152ull;      // 2 MB float/flag region
    if (ws_size < BUF_OFF + 5 * TEN) return;

    char* ws = (char*)d_ws;
    int*   dflag  = (int*)ws;
    float* fb     = (float*)ws;
    float* sums   = fb + 256;                // 16 x 256
    float* scales = fb + 256 + 4096;         // 16 x 256
    float* parts  = fb + 256 + 8192;         // 3 x 131072
    float* xcat   = parts + 3 * 131072;      // 32 x 1024
    u16* buf[5];
    for (int i = 0; i < 5; i++) buf[i] = (u16*)(ws + BUF_OFF + (size_t)i * TEN);

    // per-head buffer rotation (liveness-checked)
    const int qsrc[4] = {-1, 0, 3, 1}, qdst[4] = {0, 3, 1, 4};
    const int ksrc[4] = {-1, 1, 4, 2}, kdst[4] = {1, 4, 2, 0};
    const int vsrc[4] = {-1, 2, 0, 3}, vdst[4] = {2, 0, 3, 1};
    const int x1i[4]  = {3, 1, 4, 2},  lgi[4]  = {4, 2, 0, 3};

    detect_k<<<dim3(1), dim3(256), 0, stream>>>((const unsigned int*)d_in[0], dflag);
    hipMemsetAsync(sums, 0, 4096 * sizeof(float), stream);

    for (int h = 0; h < 4; h++) {
        const u16* qi = h ? (const u16*)buf[qsrc[h]] : q16;
        const u16* ki = h ? (const u16*)buf[ksrc[h]] : k16;
        const u16* vi = h ? (const u16*)buf[vsrc[h]] : v16;
        const float* qif = h ? nullptr : qf;
        const float* kif = h ? nullptr : kf;
        const float* vif = h ? nullptr : vf;
        const int ext = (h == 0) ? 1 : 0;
        u16* qo = buf[qdst[h]];
        u16* ko = buf[kdst[h]];
        u16* vo = buf[vdst[h]];
        u16* x1b = buf[x1i[h]];
        u16* lgb = buf[lgi[h]];
        float* sum1 = sums + (h * 4 + 0) * 256; float* ss1 = sums + (h * 4 + 1) * 256;
        float* sum2 = sums + (h * 4 + 2) * 256; float* ss2 = sums + (h * 4 + 3) * 256;
        float* sc1 = scales + (h * 4 + 0) * 256; float* sh1 = scales + (h * 4 + 1) * 256;
        float* sc2 = scales + (h * 4 + 2) * 256; float* sh2 = scales + (h * 4 + 3) * 256;

        gemm_k<0><<<dim3(1024), dim3(256), 0, stream>>>(
            qi, qif, ext, nullptr, nullptr, nullptr,
            wq16 + h * 65536, wqf + h * 65536, bq16 + h * 256, bqf + h * 256, dflag, qo);
        gemm_k<0><<<dim3(1024), dim3(256), 0, stream>>>(
            ki, kif, ext, nullptr, nullptr, nullptr,
            wk16 + h * 65536, wkf + h * 65536, bk16 + h * 256, bkf + h * 256, dflag, ko);
        gemm_k<0><<<dim3(1024), dim3(256), 0, stream>>>(
            vi, vif, ext, nullptr, nullptr, nullptr,
            wv16 + h * 65536, wvf + h * 65536, bv16 + h * 256, bvf + h * 256, dflag, vo);
        stats_k<true><<<dim3(256), dim3(256), 0, stream>>>(ko, qo, sum1, ss1);
        finalize_k<<<dim3(1), dim3(256), 0, stream>>>(
            sum1, ss1, g116 + h * 256, g1f + h * 256, be116 + h * 256, be1f + h * 256,
            dflag, sc1, sh1);
        gemm_k<1><<<dim3(1024), dim3(256), 0, stream>>>(
            ko, nullptr, 0, qo, sc1, sh1,
            wl116 + h * 65536, wl1f + h * 65536, bl116 + h * 256, bl1f + h * 256, dflag, x1b);
        stats_k<false><<<dim3(256), dim3(256), 0, stream>>>(x1b, nullptr, sum2, ss2);
        finalize_k<<<dim3(1), dim3(256), 0, stream>>>(
            sum2, ss2, g216 + h * 256, g2f + h * 256, be216 + h * 256, be2f + h * 256,
            dflag, sc2, sh2);
        gemm_k<2><<<dim3(1024), dim3(256), 0, stream>>>(
            x1b, nullptr, 0, nullptr, sc2, sh2,
            wl216 + h * 65536, wl2f + h * 65536, bl216 + h * 256, bl2f + h * 256, dflag, lgb);
        softmax_chunk_k<<<dim3(32, 16), dim3(256), 0, stream>>>(
            lgb, vo, parts, parts + 131072, parts + 2 * 131072);
        softmax_merge_k<<<dim3(32), dim3(256), 0, stream>>>(
            parts, parts + 131072, parts + 2 * 131072, xcat, h);
    }
    mlp_k<<<dim3(32), dim3(256), 0, stream>>>(
        xcat, mw016, mw0f, mb016, mb0f, mw116, mw1f, mb116, mb1f,
        mw216, mw2f, mb216, mb2f, dflag, (u16*)d_out, (float*)d_out);
}

// Round 4
// 1316.714 us; speedup vs baseline: 1.1513x; 1.1513x over previous
//
#include <hip/hip_runtime.h>
#include <hip/hip_bf16.h>

// vector_attention: S=2048, B=32, D=256, H=4. fp32 accumulate everywhere.
// Dtype-adaptive (bf16 or f32 external tensors, detected on device).
// Round 4: cheap detect; stats/finalize fused into gemm epilogues; LDS-staged
// coalesced C stores; packed bf16 converts. Numerics value-identical to r3.

typedef short  s16x8 __attribute__((ext_vector_type(8)));
typedef float  f32x4 __attribute__((ext_vector_type(4)));
typedef unsigned short u16;

__device__ __forceinline__ float bu2f(u16 u) {
    union { unsigned int i; float f; } c; c.i = ((unsigned int)u) << 16; return c.f;
}
__device__ __forceinline__ float bs2f(short s) { return bu2f((u16)s); }
__device__ __forceinline__ u16 f2bu(float f) {  // RNE
    union { float f; unsigned int i; } c; c.f = f;
    unsigned int u = c.i;
    u += 0x7fffu + ((u >> 16) & 1u);
    return (u16)(u >> 16);
}
__device__ __forceinline__ unsigned int pack2(float a, float b) {  // v_cvt_pk_bf16_f32
    __hip_bfloat162 h = __float22bfloat162_rn(make_float2(a, b));
    union { __hip_bfloat162 h; unsigned int u; } c; c.h = h; return c.u;
}

// ---------------------------------------------------------------------------
// Dtype probe (16K samples from first 64 KB of q). flag=1 bf16, 0 f32.
// ---------------------------------------------------------------------------
__global__ __launch_bounds__(256) void detect_k(const unsigned int* __restrict__ qw,
                                                int* __restrict__ flag)
{
    __shared__ int cnt[256];
    const int t = threadIdx.x;
    int c = 0;
    for (int i = 0; i < 64; i++) {
        const unsigned int w = qw[t + i * 256];
        const unsigned int e = (w >> 7) & 0xFFu;
        c += (e >= 96u && e <= 141u) ? 1 : 0;
    }
    cnt[t] = c;
    __syncthreads();
    for (int s = 128; s > 0; s >>= 1) {
        if (t < s) cnt[t] += cnt[t + s];
        __syncthreads();
    }
    if (t == 0) *flag = (cnt[0] > 8192) ? 1 : 0;
}

// ---------------------------------------------------------------------------
// Unified GEMM: C[65536,256] = op(A)[65536,256] @ W[256,256]^T + bias.
// AM 0: a = A  (EXTA: external, f32-capable). AM 1: a = relu((A-A2)*sc+sh).
// AM 2: a = relu(A*sc+sh). AM>0 computes sc/sh in-block from raw sums+g/be.
// DIFFSTATS: epilogue accumulates per-channel stats of (C - Qd).
// OUTSTATS:  epilogue accumulates per-channel stats of C.
// Tile 128x128, BK=32, 4 waves of 64x64 (4x4 MFMA 16x16x32 bf16).
// Epilogue stages C in LDS (aliases As/Bs) for coalesced 16B stores.
// ---------------------------------------------------------------------------
template<int AM, bool EXTA, bool DIFFSTATS, bool OUTSTATS>
__global__ __launch_bounds__(256) void gemm_k(
    const u16* __restrict__ A, const float* __restrict__ Af,
    const u16* __restrict__ A2,
    const u16* __restrict__ Qd,
    const u16* __restrict__ W, const float* __restrict__ Wf,
    const u16* __restrict__ bias, const float* __restrict__ biasf,
    const u16* __restrict__ g, const float* __restrict__ gf,
    const u16* __restrict__ be, const float* __restrict__ bef,
    const float* __restrict__ sumIn, const float* __restrict__ ssIn,
    float* __restrict__ sumOut, float* __restrict__ ssOut,
    const int* __restrict__ dflag,
    u16* __restrict__ C)
{
    __shared__ __align__(16) u16 smem[16384];     // 32 KB: As|Bs in K-loop, Cs in epilogue
    __shared__ float sc_s[256], sh_s[256];
    u16* As = smem;            // 128x32
    u16* Bs = smem + 4096;     // 128x32

    const int f32in = (*dflag == 0);
    const int tid   = threadIdx.x;
    const int tileN = blockIdx.x & 1;
    const int tileM = blockIdx.x >> 1;
    const int lane  = tid & 63;
    const int wave  = tid >> 6;
    const int wm    = wave & 1;
    const int wn    = wave >> 1;
    const int lrow  = lane & 15;
    const int quad  = lane >> 4;

    if (AM != 0) {
        const int c = tid;
        const float mean = sumIn[c] * (1.f / 65536.f);
        const float var  = ssIn[c] * (1.f / 65536.f) - mean * mean;
        const float rstd = rsqrtf(var + 1e-5f);
        const float gg = f32in ? gf[c] : bu2f(g[c]);
        const float bb = f32in ? bef[c] : bu2f(be[c]);
        sc_s[c] = rstd * gg;
        sh_s[c] = bb - mean * rstd * gg;
        __syncthreads();
    }

    f32x4 acc[4][4];
#pragma unroll
    for (int i = 0; i < 4; i++)
#pragma unroll
        for (int j = 0; j < 4; j++) acc[i][j] = (f32x4){0.f, 0.f, 0.f, 0.f};

    const int  rA   = tid >> 2;
    const int  kq   = (tid & 3) << 3;
    const long rowA = (long)tileM * 128;
    const long rowB = (long)tileN * 128;

    for (int k0 = 0; k0 < 256; k0 += 32) {
        if (k0) __syncthreads();
#pragma unroll
        for (int j = 0; j < 2; j++) {
            const int  r   = j * 64 + rA;
            const long off = (rowA + r) * 256 + k0 + kq;
            u16* dstA = As + j * 2048 + tid * 8;

            if constexpr (AM == 0) {
                if (EXTA && f32in) {
                    const float* p = Af + off;
                    f32x4 a = *(const f32x4*)p;
                    f32x4 b = *(const f32x4*)(p + 4);
                    union { s16x8 v; unsigned int w[4]; } o;
                    o.w[0] = pack2(a[0], a[1]); o.w[1] = pack2(a[2], a[3]);
                    o.w[2] = pack2(b[0], b[1]); o.w[3] = pack2(b[2], b[3]);
                    *(s16x8*)dstA = o.v;
                } else {
                    *(s16x8*)dstA = *(const s16x8*)(A + off);
                }
            } else {
                s16x8 xv = *(const s16x8*)(A + off);
                s16x8 yv;
                if constexpr (AM == 1) yv = *(const s16x8*)(A2 + off);
                f32x4 sc0 = *(const f32x4*)(sc_s + k0 + kq);
                f32x4 sc1 = *(const f32x4*)(sc_s + k0 + kq + 4);
                f32x4 sh0 = *(const f32x4*)(sh_s + k0 + kq);
                f32x4 sh1 = *(const f32x4*)(sh_s + k0 + kq + 4);
                float d[8];
#pragma unroll
                for (int e = 0; e < 8; e++) {
                    float x = bs2f(xv[e]);
                    if constexpr (AM == 1) x -= bs2f(yv[e]);
                    const float sc = (e < 4) ? sc0[e & 3] : sc1[e & 3];
                    const float sh = (e < 4) ? sh0[e & 3] : sh1[e & 3];
                    d[e] = fmaxf(fmaf(x, sc, sh), 0.f);
                }
                union { s16x8 v; unsigned int w[4]; } o;
                o.w[0] = pack2(d[0], d[1]); o.w[1] = pack2(d[2], d[3]);
                o.w[2] = pack2(d[4], d[5]); o.w[3] = pack2(d[6], d[7]);
                *(s16x8*)dstA = o.v;
            }

            const long offW = (rowB + r) * 256 + k0 + kq;
            u16* dstB = Bs + j * 2048 + tid * 8;
            if (f32in) {
                const float* p = Wf + offW;
                f32x4 a = *(const f32x4*)p;
                f32x4 b = *(const f32x4*)(p + 4);
                union { s16x8 v; unsigned int w[4]; } o;
                o.w[0] = pack2(a[0], a[1]); o.w[1] = pack2(a[2], a[3]);
                o.w[2] = pack2(b[0], b[1]); o.w[3] = pack2(b[2], b[3]);
                *(s16x8*)dstB = o.v;
            } else {
                *(s16x8*)dstB = *(const s16x8*)(W + offW);
            }
        }
        __syncthreads();

        s16x8 af[4], bf[4];
#pragma unroll
        for (int im = 0; im < 4; im++)
            af[im] = *(const s16x8*)(As + (wm * 64 + im * 16 + lrow) * 32 + quad * 8);
#pragma unroll
        for (int in = 0; in < 4; in++)
            bf[in] = *(const s16x8*)(Bs + (wn * 64 + in * 16 + lrow) * 32 + quad * 8);
#pragma unroll
        for (int im = 0; im < 4; im++)
#pragma unroll
            for (int in = 0; in < 4; in++)
                acc[im][in] = __builtin_amdgcn_mfma_f32_16x16x32_bf16(
                    af[im], bf[in], acc[im][in], 0, 0, 0);
    }

    // ---- epilogue: stage bf16 C-tile in LDS, then coalesced stores ----
    __syncthreads();                       // all waves done reading As/Bs
    u16* Cs = smem;                        // 128x128
#pragma unroll
    for (int in = 0; in < 4; in++) {
        const int col = wn * 64 + in * 16 + lrow;            // local col
        const int gcol = (int)rowB + col;
        const float bv = f32in ? biasf[gcol] : bu2f(bias[gcol]);
#pragma unroll
        for (int im = 0; im < 4; im++) {
            const int r0 = wm * 64 + im * 16 + quad * 4;
#pragma unroll
            for (int e = 0; e < 4; e++)
                Cs[(r0 + e) * 128 + col] = f2bu(acc[im][in][e] + bv);
        }
    }
    __syncthreads();

    if (DIFFSTATS || OUTSTATS) {
        const int colL = tid & 127;
        const int half = tid >> 7;
        float s = 0.f, qs = 0.f;
#pragma unroll 8
        for (int r = half * 64; r < half * 64 + 64; r++) {
            float x = bu2f(Cs[r * 128 + colL]);
            if (DIFFSTATS) x -= bu2f(Qd[(rowA + r) * 256 + rowB + colL]);
            s += x; qs += x * x;
        }
        atomicAdd(&sumOut[rowB + colL], s);
        atomicAdd(&ssOut[rowB + colL], qs);
    }

#pragma unroll
    for (int it = 0; it < 8; it++) {
        const int r  = it * 16 + (tid >> 4);
        const int c8 = (tid & 15) * 8;
        *(s16x8*)(C + (rowA + r) * 256 + rowB + c8) = *(const s16x8*)(Cs + r * 128 + c8);
    }
}

// ---------------------------------------------------------------------------
// Online softmax over S fused with weighted v-sum, chunked (ws bf16).
// ---------------------------------------------------------------------------
__global__ __launch_bounds__(256) void softmax_chunk_k(
    const u16* __restrict__ L, const u16* __restrict__ V,
    float* __restrict__ pm, float* __restrict__ pl, float* __restrict__ pa)
{
    const int d = threadIdx.x, b = blockIdx.x, ch = blockIdx.y;
    float m = -3.0e38f, l = 0.f, acc = 0.f;
    const long base = ((long)ch * 128 * 32 + b) * 256 + d;
    for (int si = 0; si < 128; si++) {
        const long idx = base + (long)si * 32 * 256;
        const float x = bu2f(L[idx]);
        const float v = bu2f(V[idx]);
        const float mn = fmaxf(m, x);
        const float c  = __expf(m - mn);
        const float e  = __expf(x - mn);
        l   = l * c + e;
        acc = acc * c + e * v;
        m = mn;
    }
    const int p = (ch * 32 + b) * 256 + d;
    pm[p] = m; pl[p] = l; pa[p] = acc;
}

__global__ __launch_bounds__(256) void softmax_merge_k(
    const float* __restrict__ pm, const float* __restrict__ pl,
    const float* __restrict__ pa, float* __restrict__ xcat, int head)
{
    const int d = threadIdx.x, b = blockIdx.x;
    float M = -3.0e38f, L = 0.f, A = 0.f;
    for (int ch = 0; ch < 16; ch++) {
        const int p = (ch * 32 + b) * 256 + d;
        const float m = pm[p], l = pl[p], a = pa[p];
        const float mn = fmaxf(M, m);
        const float c1 = __expf(M - mn), c2 = __expf(m - mn);
        L = L * c1 + l * c2;
        A = A * c1 + a * c2;
        M = mn;
    }
    xcat[b * 1024 + head * 256 + d] = A / L;
}

// ---------------------------------------------------------------------------
// Final MLP: [32,1024] -> relu -> 256 -> relu -> 256.
// ---------------------------------------------------------------------------
__global__ __launch_bounds__(256) void mlp_k(
    const float* __restrict__ xcat,
    const u16* __restrict__ mw0, const float* __restrict__ mw0f,
    const u16* __restrict__ mb0, const float* __restrict__ mb0f,
    const u16* __restrict__ mw1, const float* __restrict__ mw1f,
    const u16* __restrict__ mb1, const float* __restrict__ mb1f,
    const u16* __restrict__ mw2, const float* __restrict__ mw2f,
    const u16* __restrict__ mb2, const float* __restrict__ mb2f,
    const int* __restrict__ dflag,
    u16* __restrict__ out, float* __restrict__ outf)
{
    __shared__ float h0[1024];
    __shared__ float h1[256];
    __shared__ float h2[256];
    const int f32in = (*dflag == 0);
    const int j = threadIdx.x, b = blockIdx.x;
#pragma unroll
    for (int i = 0; i < 4; i++) h0[j + i * 256] = xcat[b * 1024 + j + i * 256];
    __syncthreads();

    float a0 = f32in ? mb0f[j] : bu2f(mb0[j]);
    if (f32in) {
        for (int k4 = 0; k4 < 256; k4++) {
            f32x4 wv = *(const f32x4*)(mw0f + j * 1024 + k4 * 4);
#pragma unroll
            for (int e = 0; e < 4; e++) a0 += h0[k4 * 4 + e] * wv[e];
        }
    } else {
        for (int k8 = 0; k8 < 128; k8++) {
            s16x8 wv = *(const s16x8*)(mw0 + j * 1024 + k8 * 8);
#pragma unroll
            for (int e = 0; e < 8; e++) a0 += h0[k8 * 8 + e] * bs2f(wv[e]);
        }
    }
    h1[j] = fmaxf(a0, 0.f);
    __syncthreads();

    float a1 = f32in ? mb1f[j] : bu2f(mb1[j]);
    if (f32in) {
        for (int k4 = 0; k4 < 64; k4++) {
            f32x4 wv = *(const f32x4*)(mw1f + j * 256 + k4 * 4);
#pragma unroll
            for (int e = 0; e < 4; e++) a1 += h1[k4 * 4 + e] * wv[e];
        }
    } else {
        for (int k8 = 0; k8 < 32; k8++) {
            s16x8 wv = *(const s16x8*)(mw1 + j * 256 + k8 * 8);
#pragma unroll
            for (int e = 0; e < 8; e++) a1 += h1[k8 * 8 + e] * bs2f(wv[e]);
        }
    }
    h2[j] = fmaxf(a1, 0.f);
    __syncthreads();

    float a2 = f32in ? mb2f[j] : bu2f(mb2[j]);
    if (f32in) {
        for (int k4 = 0; k4 < 64; k4++) {
            f32x4 wv = *(const f32x4*)(mw2f + j * 256 + k4 * 4);
#pragma unroll
            for (int e = 0; e < 4; e++) a2 += h2[k4 * 4 + e] * wv[e];
        }
    } else {
        for (int k8 = 0; k8 < 32; k8++) {
            s16x8 wv = *(const s16x8*)(mw2 + j * 256 + k8 * 8);
#pragma unroll
            for (int e = 0; e < 8; e++) a2 += h2[k8 * 8 + e] * bs2f(wv[e]);
        }
    }
    if (f32in) outf[b * 256 + j] = a2;
    else       out[b * 256 + j] = f2bu(a2);
}

// ---------------------------------------------------------------------------
extern "C" void kernel_launch(void* const* d_in, const int* in_sizes, int n_in,
                              void* d_out, int out_size, void* d_ws, size_t ws_size,
                              hipStream_t stream)
{
    const u16 *q16 = (const u16*)d_in[0], *k16 = (const u16*)d_in[1], *v16 = (const u16*)d_in[2];
    const u16 *wq16 = (const u16*)d_in[3], *bq16 = (const u16*)d_in[4];
    const u16 *wk16 = (const u16*)d_in[5], *bk16 = (const u16*)d_in[6];
    const u16 *wv16 = (const u16*)d_in[7], *bv16 = (const u16*)d_in[8];
    const u16 *g116 = (const u16*)d_in[9], *be116 = (const u16*)d_in[10];
    const u16 *wl116 = (const u16*)d_in[11], *bl116 = (const u16*)d_in[12];
    const u16 *g216 = (const u16*)d_in[13], *be216 = (const u16*)d_in[14];
    const u16 *wl216 = (const u16*)d_in[15], *bl216 = (const u16*)d_in[16];
    const u16 *mw016 = (const u16*)d_in[17], *mb016 = (const u16*)d_in[18];
    const u16 *mw116 = (const u16*)d_in[19], *mb116 = (const u16*)d_in[20];
    const u16 *mw216 = (const u16*)d_in[21], *mb216 = (const u16*)d_in[22];
    const float *qf = (const float*)d_in[0], *kf = (const float*)d_in[1], *vf = (const float*)d_in[2];
    const float *wqf = (const float*)d_in[3], *bqf = (const float*)d_in[4];
    const float *wkf = (const float*)d_in[5], *bkf = (const float*)d_in[6];
    const float *wvf = (const float*)d_in[7], *bvf = (const float*)d_in[8];
    const float *g1f = (const float*)d_in[9], *be1f = (const float*)d_in[10];
    const float *wl1f = (const float*)d_in[11], *bl1f = (const float*)d_in[12];
    const float *g2f = (const float*)d_in[13], *be2f = (const float*)d_in[14];
    const float *wl2f = (const float*)d_in[15], *bl2f = (const float*)d_in[16];
    const float *mw0f = (const float*)d_in[17], *mb0f = (const float*)d_in[18];
    const float *mw1f = (const float*)d_in[19], *mb1f = (const float*)d_in[20];
    const float *mw2f = (const float*)d_in[21], *mb2f = (const float*)d_in[22];

    const size_t TEN = 33554432ull;
    const size_t BUF_OFF = 2097152ull;
    if (ws_size < BUF_OFF + 5 * TEN) return;   // 162 MB (verified fits in r3)

    char* ws = (char*)d_ws;
    int*   dflag  = (int*)ws;
    float* fb     = (float*)ws;
    float* sums   = fb + 256;                // 16 x 256
    float* parts  = fb + 256 + 4096;         // 3 x 131072
    float* xcat   = parts + 3 * 131072;      // 32 x 1024
    u16* buf[5];
    for (int i = 0; i < 5; i++) buf[i] = (u16*)(ws + BUF_OFF + (size_t)i * TEN);

    // per-head buffer rotation (liveness-checked)
    const int qsrc[4] = {-1, 0, 3, 1}, qdst[4] = {0, 3, 1, 4};
    const int ksrc[4] = {-1, 1, 4, 2}, kdst[4] = {1, 4, 2, 0};
    const int vsrc[4] = {-1, 2, 0, 3}, vdst[4] = {2, 0, 3, 1};
    const int x1i[4]  = {3, 1, 4, 2},  lgi[4]  = {4, 2, 0, 3};

    detect_k<<<dim3(1), dim3(256), 0, stream>>>((const unsigned int*)d_in[0], dflag);
    hipMemsetAsync(sums, 0, 4096 * sizeof(float), stream);

    for (int h = 0; h < 4; h++) {
        const u16* qi = h ? (const u16*)buf[qsrc[h]] : q16;
        const u16* ki = h ? (const u16*)buf[ksrc[h]] : k16;
        const u16* vi = h ? (const u16*)buf[vsrc[h]] : v16;
        u16* qo = buf[qdst[h]];
        u16* ko = buf[kdst[h]];
        u16* vo = buf[vdst[h]];
        u16* x1b = buf[x1i[h]];
        u16* lgb = buf[lgi[h]];
        float* sum1 = sums + (h * 4 + 0) * 256; float* ss1 = sums + (h * 4 + 1) * 256;
        float* sum2 = sums + (h * 4 + 2) * 256; float* ss2 = sums + (h * 4 + 3) * 256;

        // q' projection (plain)
        if (h == 0)
            gemm_k<0, true, false, false><<<dim3(1024), dim3(256), 0, stream>>>(
                qi, qf, nullptr, nullptr, wq16 + h * 65536, wqf + h * 65536,
                bq16 + h * 256, bqf + h * 256, nullptr, nullptr, nullptr, nullptr,
                nullptr, nullptr, nullptr, nullptr, dflag, qo);
        else
            gemm_k<0, false, false, false><<<dim3(1024), dim3(256), 0, stream>>>(
                qi, nullptr, nullptr, nullptr, wq16 + h * 65536, wqf + h * 65536,
                bq16 + h * 256, bqf + h * 256, nullptr, nullptr, nullptr, nullptr,
                nullptr, nullptr, nullptr, nullptr, dflag, qo);
        // v' projection (plain)
        if (h == 0)
            gemm_k<0, true, false, false><<<dim3(1024), dim3(256), 0, stream>>>(
                vi, vf, nullptr, nullptr, wv16 + h * 65536, wvf + h * 65536,
                bv16 + h * 256, bvf + h * 256, nullptr, nullptr, nullptr, nullptr,
                nullptr, nullptr, nullptr, nullptr, dflag, vo);
        else
            gemm_k<0, false, false, false><<<dim3(1024), dim3(256), 0, stream>>>(
                vi, nullptr, nullptr, nullptr, wv16 + h * 65536, wvf + h * 65536,
                bv16 + h * 256, bvf + h * 256, nullptr, nullptr, nullptr, nullptr,
                nullptr, nullptr, nullptr, nullptr, dflag, vo);
        // k' projection + fused diff-stats vs q' (must follow q' gemm)
        if (h == 0)
            gemm_k<0, true, true, false><<<dim3(1024), dim3(256), 0, stream>>>(
                ki, kf, nullptr, qo, wk16 + h * 65536, wkf + h * 65536,
                bk16 + h * 256, bkf + h * 256, nullptr, nullptr, nullptr, nullptr,
                nullptr, nullptr, sum1, ss1, dflag, ko);
        else
            gemm_k<0, false, true, false><<<dim3(1024), dim3(256), 0, stream>>>(
                ki, nullptr, nullptr, qo, wk16 + h * 65536, wkf + h * 65536,
                bk16 + h * 256, bkf + h * 256, nullptr, nullptr, nullptr, nullptr,
                nullptr, nullptr, sum1, ss1, dflag, ko);
        // x1 = relu(bn1(k'-q')) @ wl1^T + bl1, fused x1-stats
        gemm_k<1, false, false, true><<<dim3(1024), dim3(256), 0, stream>>>(
            ko, nullptr, qo, nullptr, wl116 + h * 65536, wl1f + h * 65536,
            bl116 + h * 256, bl1f + h * 256, g116 + h * 256, g1f + h * 256,
            be116 + h * 256, be1f + h * 256, sum1, ss1, sum2, ss2, dflag, x1b);
        // logits = relu(bn2(x1)) @ wl2^T + bl2
        gemm_k<2, false, false, false><<<dim3(1024), dim3(256), 0, stream>>>(
            x1b, nullptr, nullptr, nullptr, wl216 + h * 65536, wl2f + h * 65536,
            bl216 + h * 256, bl2f + h * 256, g216 + h * 256, g2f + h * 256,
            be216 + h * 256, be2f + h * 256, sum2, ss2, nullptr, nullptr, dflag, lgb);
        softmax_chunk_k<<<dim3(32, 16), dim3(256), 0, stream>>>(
            lgb, vo, parts, parts + 131072, parts + 2 * 131072);
        softmax_merge_k<<<dim3(32), dim3(256), 0, stream>>>(
            parts, parts + 131072, parts + 2 * 131072, xcat, h);
    }
    mlp_k<<<dim3(32), dim3(256), 0, stream>>>(
        xcat, mw016, mw0f, mb016, mb0f, mw116, mw1f, mb116, mb1f,
        mw216, mw2f, mb216, mb2f, dflag, (u16*)d_out, (float*)d_out);
}

// Round 5
// 897.103 us; speedup vs baseline: 1.6898x; 1.4677x over previous
//
#include <hip/hip_runtime.h>
#include <hip/hip_bf16.h>

// vector_attention: S=2048, B=32, D=256, H=4. fp32 accumulate.
// Round 5: 64x128 tiles (2048 blocks, ~5 blocks/CU), global_load_lds staging,
// 16-copy spread stats atomics (consumer reduces), weights pre-converted to
// bf16 once, q+v projections batched, softmax partials in dead ws buffer.

typedef short  s16x8 __attribute__((ext_vector_type(8)));
typedef float  f32x4 __attribute__((ext_vector_type(4)));
typedef unsigned short u16;

constexpr int NC = 16;   // stat shadow copies

__device__ __forceinline__ float bu2f(u16 u) {
    union { unsigned int i; float f; } c; c.i = ((unsigned int)u) << 16; return c.f;
}
__device__ __forceinline__ float bs2f(short s) { return bu2f((u16)s); }
__device__ __forceinline__ u16 f2bu(float f) {  // RNE
    union { float f; unsigned int i; } c; c.f = f;
    unsigned int u = c.i;
    u += 0x7fffu + ((u >> 16) & 1u);
    return (u16)(u >> 16);
}
__device__ __forceinline__ unsigned int pack2(float a, float b) {  // v_cvt_pk_bf16_f32
    __hip_bfloat162 h = __float22bfloat162_rn(make_float2(a, b));
    union { __hip_bfloat162 h; unsigned int u; } c; c.h = h; return c.u;
}

// ---------------------------------------------------------------------------
// Dtype probe on q (first 64 KB). flag=1 bf16, 0 f32.
// ---------------------------------------------------------------------------
__global__ __launch_bounds__(256) void detect_k(const unsigned int* __restrict__ qw,
                                                int* __restrict__ flag)
{
    __shared__ int cnt[256];
    const int t = threadIdx.x;
    int c = 0;
    for (int i = 0; i < 64; i++) {
        const unsigned int w = qw[t + i * 256];
        const unsigned int e = (w >> 7) & 0xFFu;
        c += (e >= 96u && e <= 141u) ? 1 : 0;
    }
    cnt[t] = c;
    __syncthreads();
    for (int s = 128; s > 0; s >>= 1) {
        if (t < s) cnt[t] += cnt[t + s];
        __syncthreads();
    }
    if (t == 0) *flag = (cnt[0] > 8192) ? 1 : 0;
}

// ---------------------------------------------------------------------------
// Weight pre-convert: 5 tensors x [4,256,256] -> bf16 in ws.
// ---------------------------------------------------------------------------
__global__ __launch_bounds__(256) void wconv_k(
    const void* w0, const void* w1, const void* w2, const void* w3, const void* w4,
    const int* __restrict__ dflag, u16* __restrict__ dst)
{
    const void* srcs[5] = {w0, w1, w2, w3, w4};
    const int y = blockIdx.y;
    const int idx = blockIdx.x * 1024 + threadIdx.x * 4;
    u16* d = dst + y * 262144 + idx;
    if (*dflag == 0) {
        f32x4 v = *(const f32x4*)((const float*)srcs[y] + idx);
        unsigned int lo = pack2(v[0], v[1]);
        unsigned int hi = pack2(v[2], v[3]);
        *(unsigned long long*)d = ((unsigned long long)hi << 32) | lo;
    } else {
        *(unsigned long long*)d = *(const unsigned long long*)((const u16*)srcs[y] + idx);
    }
}

// ---------------------------------------------------------------------------
// GEMM core: C[65536,256] = op(A) @ W[256,256]^T + bias. Tile 64(M)x128(N),
// BK=32, 4 waves (2x2), wave = 32x64 (2x4 MFMA 16x16x32 bf16).
// AM 0: a=A (EXTA: external, f32-capable). AM 1: a=relu((A-A2)*sc+sh).
// AM 2: a=relu(A*sc+sh). AM>0 reduces NC-copy stats in prologue -> sc/sh.
// STATS 1: epilogue stats of (C - Qd); STATS 2: stats of C. 16-copy atomics.
// ---------------------------------------------------------------------------
template<int AM, bool EXTA, int STATS>
__device__ __forceinline__ void gemm_core(
    const u16* __restrict__ A, const float* __restrict__ Af,
    const u16* __restrict__ A2, const u16* __restrict__ Qd,
    const u16* __restrict__ Wb,
    const u16* __restrict__ bias16, const float* __restrict__ biasf,
    const u16* __restrict__ g16, const float* __restrict__ gf,
    const u16* __restrict__ be16, const float* __restrict__ bef,
    const float* __restrict__ statsIn, float* __restrict__ statsOut,
    const int f32in, u16* __restrict__ C, const int bx)
{
    __shared__ __align__(16) u16 smem[8192];   // K-loop: As(2048)|Bs(4096); epilogue: Cs 64x128
    __shared__ float sc_s[256], sh_s[256];
    __shared__ float red_s[256];
    u16* As = smem;
    u16* Bs = smem + 2048;

    const int tid   = threadIdx.x;
    const int tileN = bx & 1;
    const int tileM = bx >> 1;
    const int lane  = tid & 63;
    const int wave  = tid >> 6;
    const int wm    = wave & 1;
    const int wn    = wave >> 1;
    const int lrow  = lane & 15;
    const int quad  = lane >> 4;

    if constexpr (AM != 0) {
        const int c = tid;
        float s = 0.f, q = 0.f;
#pragma unroll
        for (int i = 0; i < NC; i++) {
            s += statsIn[i * 256 + c];
            q += statsIn[(NC + i) * 256 + c];
        }
        const float mean = s * (1.f / 65536.f);
        const float var  = q * (1.f / 65536.f) - mean * mean;
        const float rstd = rsqrtf(var + 1e-5f);
        const float gg = f32in ? gf[c] : bu2f(g16[c]);
        const float bb = f32in ? bef[c] : bu2f(be16[c]);
        sc_s[c] = rstd * gg;
        sh_s[c] = bb - mean * rstd * gg;
        __syncthreads();
    }

    f32x4 acc[2][4];
#pragma unroll
    for (int i = 0; i < 2; i++)
#pragma unroll
        for (int j = 0; j < 4; j++) acc[i][j] = (f32x4){0.f, 0.f, 0.f, 0.f};

    const int  rA   = tid >> 2;        // 0..63
    const int  kq   = (tid & 3) << 3;  // 0,8,16,24
    const long rowA = (long)tileM * 64;
    const int  rowB = tileN * 128;

    for (int k0 = 0; k0 < 256; k0 += 32) {
        if (k0) __syncthreads();
        // W staging (pre-converted bf16): 2 async 16B chunks per thread pattern
        {
            const u16* gw = Wb + (rowB + rA) * 256 + k0 + kq;
            __builtin_amdgcn_global_load_lds(
                (const __attribute__((address_space(1))) void*)gw,
                (__attribute__((address_space(3))) void*)(Bs + tid * 8), 16, 0, 0);
            __builtin_amdgcn_global_load_lds(
                (const __attribute__((address_space(1))) void*)(gw + 64 * 256),
                (__attribute__((address_space(3))) void*)(Bs + 2048 + tid * 8), 16, 0, 0);
        }
        const long offA = (rowA + rA) * 256 + k0 + kq;
        if constexpr (AM == 0) {
            if (EXTA && f32in) {
                const float* p = Af + offA;
                f32x4 a = *(const f32x4*)p;
                f32x4 b = *(const f32x4*)(p + 4);
                union { s16x8 v; unsigned int w[4]; } o;
                o.w[0] = pack2(a[0], a[1]); o.w[1] = pack2(a[2], a[3]);
                o.w[2] = pack2(b[0], b[1]); o.w[3] = pack2(b[2], b[3]);
                *(s16x8*)(As + tid * 8) = o.v;
            } else {
                __builtin_amdgcn_global_load_lds(
                    (const __attribute__((address_space(1))) void*)(A + offA),
                    (__attribute__((address_space(3))) void*)(As + tid * 8), 16, 0, 0);
            }
        } else {
            s16x8 xv = *(const s16x8*)(A + offA);
            s16x8 yv;
            if constexpr (AM == 1) yv = *(const s16x8*)(A2 + offA);
            float d[8];
#pragma unroll
            for (int e = 0; e < 8; e++) {
                float x = bs2f(xv[e]);
                if constexpr (AM == 1) x -= bs2f(yv[e]);
                d[e] = fmaxf(fmaf(x, sc_s[k0 + kq + e], sh_s[k0 + kq + e]), 0.f);
            }
            union { s16x8 v; unsigned int w[4]; } o;
            o.w[0] = pack2(d[0], d[1]); o.w[1] = pack2(d[2], d[3]);
            o.w[2] = pack2(d[4], d[5]); o.w[3] = pack2(d[6], d[7]);
            *(s16x8*)(As + tid * 8) = o.v;
        }
        __syncthreads();   // drains vmcnt (async LDS loads) + lgkm

        s16x8 af[2], bf[4];
#pragma unroll
        for (int im = 0; im < 2; im++)
            af[im] = *(const s16x8*)(As + (wm * 32 + im * 16 + lrow) * 32 + quad * 8);
#pragma unroll
        for (int in = 0; in < 4; in++)
            bf[in] = *(const s16x8*)(Bs + (wn * 64 + in * 16 + lrow) * 32 + quad * 8);
#pragma unroll
        for (int im = 0; im < 2; im++)
#pragma unroll
            for (int in = 0; in < 4; in++)
                acc[im][in] = __builtin_amdgcn_mfma_f32_16x16x32_bf16(
                    af[im], bf[in], acc[im][in], 0, 0, 0);
    }

    // epilogue: C/D layout col=lane&15, row=quad*4+reg [m89/m91]; stage in LDS
    __syncthreads();
    u16* Cs = smem;   // 64 x 128
#pragma unroll
    for (int in = 0; in < 4; in++) {
        const int col  = wn * 64 + in * 16 + lrow;
        const int gcol = rowB + col;
        const float bv = f32in ? biasf[gcol] : bu2f(bias16[gcol]);
#pragma unroll
        for (int im = 0; im < 2; im++) {
            const int r0 = wm * 32 + im * 16 + quad * 4;
#pragma unroll
            for (int e = 0; e < 4; e++)
                Cs[(r0 + e) * 128 + col] = f2bu(acc[im][in][e] + bv);
        }
    }
    __syncthreads();

    if constexpr (STATS != 0) {
        const int colL = tid & 127;
        const int half = tid >> 7;
        float s = 0.f, qs = 0.f;
#pragma unroll 4
        for (int r = half * 32; r < half * 32 + 32; r++) {
            float x = bu2f(Cs[r * 128 + colL]);
            if constexpr (STATS == 1) x -= bu2f(Qd[(rowA + r) * 256 + rowB + colL]);
            s += x; qs += x * x;
        }
        red_s[tid] = s;
        __syncthreads();
        float sTot = 0.f;
        if (tid < 128) sTot = red_s[tid] + red_s[tid + 128];
        __syncthreads();
        red_s[tid] = qs;
        __syncthreads();
        if (tid < 128) {
            const float qTot = red_s[tid] + red_s[tid + 128];
            const int copy = tileM & (NC - 1);
            atomicAdd(&statsOut[copy * 256 + rowB + colL], sTot);
            atomicAdd(&statsOut[(NC + copy) * 256 + rowB + colL], qTot);
        }
    }

#pragma unroll
    for (int it = 0; it < 4; it++) {
        const int r  = it * 16 + (tid >> 4);
        const int c8 = (tid & 15) * 8;
        *(s16x8*)(C + (rowA + r) * 256 + rowB + c8) = *(const s16x8*)(Cs + r * 128 + c8);
    }
}

template<int AM, bool EXTA, int STATS>
__global__ __launch_bounds__(256) void gemm_k(
    const u16* A, const float* Af, const u16* A2, const u16* Qd,
    const u16* Wb, const void* bias, const void* g, const void* be, int hoff,
    const float* statsIn, float* statsOut, const int* dflag, u16* C)
{
    const int f32in = (*dflag == 0);
    gemm_core<AM, EXTA, STATS>(A, Af, A2, Qd, Wb,
        (const u16*)bias + hoff, (const float*)bias + hoff,
        (const u16*)g + hoff,    (const float*)g + hoff,
        (const u16*)be + hoff,   (const float*)be + hoff,
        statsIn, statsOut, f32in, C, blockIdx.x);
}

template<bool EXTA>
__global__ __launch_bounds__(256) void proj2_k(
    const u16* A0, const float* A0f, const u16* W0, const void* b0, u16* C0,
    const u16* A1, const float* A1f, const u16* W1, const void* b1, u16* C1,
    int hoff, const int* dflag)
{
    const int f32in = (*dflag == 0);
    const int y = blockIdx.y;
    gemm_core<0, EXTA, 0>(
        y ? A1 : A0, y ? A1f : A0f, nullptr, nullptr, y ? W1 : W0,
        (const u16*)(y ? b1 : b0) + hoff, (const float*)(y ? b1 : b0) + hoff,
        nullptr, nullptr, nullptr, nullptr, nullptr, nullptr,
        f32in, y ? C1 : C0, blockIdx.x);
}

// ---------------------------------------------------------------------------
// Online softmax over S + weighted v-sum: 32 chunks x 64 s-rows.
// ---------------------------------------------------------------------------
__global__ __launch_bounds__(256) void softmax_chunk_k(
    const u16* __restrict__ L, const u16* __restrict__ V,
    float* __restrict__ pm, float* __restrict__ pl, float* __restrict__ pa)
{
    const int d = threadIdx.x, b = blockIdx.x, ch = blockIdx.y;
    float m = -3.0e38f, l = 0.f, acc = 0.f;
    const long base = ((long)ch * 64 * 32 + b) * 256 + d;
    for (int si = 0; si < 64; si++) {
        const long idx = base + (long)si * 32 * 256;
        const float x = bu2f(L[idx]);
        const float v = bu2f(V[idx]);
        const float mn = fmaxf(m, x);
        const float c  = __expf(m - mn);
        const float e  = __expf(x - mn);
        l   = l * c + e;
        acc = acc * c + e * v;
        m = mn;
    }
    const int p = (ch * 32 + b) * 256 + d;
    pm[p] = m; pl[p] = l; pa[p] = acc;
}

__global__ __launch_bounds__(256) void softmax_merge_k(
    const float* __restrict__ pm, const float* __restrict__ pl,
    const float* __restrict__ pa, float* __restrict__ xcat, int head)
{
    const int d = threadIdx.x, b = blockIdx.x;
    float M = -3.0e38f, L = 0.f, A = 0.f;
    for (int ch = 0; ch < 32; ch++) {
        const int p = (ch * 32 + b) * 256 + d;
        const float m = pm[p], l = pl[p], a = pa[p];
        const float mn = fmaxf(M, m);
        const float c1 = __expf(M - mn), c2 = __expf(m - mn);
        L = L * c1 + l * c2;
        A = A * c1 + a * c2;
        M = mn;
    }
    xcat[b * 1024 + head * 256 + d] = A / L;
}

// ---------------------------------------------------------------------------
// Final MLP: [32,1024] -> relu -> 256 -> relu -> 256.
// ---------------------------------------------------------------------------
__global__ __launch_bounds__(256) void mlp_k(
    const float* __restrict__ xcat,
    const u16* __restrict__ mw0, const float* __restrict__ mw0f,
    const u16* __restrict__ mb0, const float* __restrict__ mb0f,
    const u16* __restrict__ mw1, const float* __restrict__ mw1f,
    const u16* __restrict__ mb1, const float* __restrict__ mb1f,
    const u16* __restrict__ mw2, const float* __restrict__ mw2f,
    const u16* __restrict__ mb2, const float* __restrict__ mb2f,
    const int* __restrict__ dflag,
    u16* __restrict__ out, float* __restrict__ outf)
{
    __shared__ float h0[1024];
    __shared__ float h1[256];
    __shared__ float h2[256];
    const int f32in = (*dflag == 0);
    const int j = threadIdx.x, b = blockIdx.x;
#pragma unroll
    for (int i = 0; i < 4; i++) h0[j + i * 256] = xcat[b * 1024 + j + i * 256];
    __syncthreads();

    float a0 = f32in ? mb0f[j] : bu2f(mb0[j]);
    if (f32in) {
        for (int k4 = 0; k4 < 256; k4++) {
            f32x4 wv = *(const f32x4*)(mw0f + j * 1024 + k4 * 4);
#pragma unroll
            for (int e = 0; e < 4; e++) a0 += h0[k4 * 4 + e] * wv[e];
        }
    } else {
        for (int k8 = 0; k8 < 128; k8++) {
            s16x8 wv = *(const s16x8*)(mw0 + j * 1024 + k8 * 8);
#pragma unroll
            for (int e = 0; e < 8; e++) a0 += h0[k8 * 8 + e] * bs2f(wv[e]);
        }
    }
    h1[j] = fmaxf(a0, 0.f);
    __syncthreads();

    float a1 = f32in ? mb1f[j] : bu2f(mb1[j]);
    if (f32in) {
        for (int k4 = 0; k4 < 64; k4++) {
            f32x4 wv = *(const f32x4*)(mw1f + j * 256 + k4 * 4);
#pragma unroll
            for (int e = 0; e < 4; e++) a1 += h1[k4 * 4 + e] * wv[e];
        }
    } else {
        for (int k8 = 0; k8 < 32; k8++) {
            s16x8 wv = *(const s16x8*)(mw1 + j * 256 + k8 * 8);
#pragma unroll
            for (int e = 0; e < 8; e++) a1 += h1[k8 * 8 + e] * bs2f(wv[e]);
        }
    }
    h2[j] = fmaxf(a1, 0.f);
    __syncthreads();

    float a2 = f32in ? mb2f[j] : bu2f(mb2[j]);
    if (f32in) {
        for (int k4 = 0; k4 < 64; k4++) {
            f32x4 wv = *(const f32x4*)(mw2f + j * 256 + k4 * 4);
#pragma unroll
            for (int e = 0; e < 4; e++) a2 += h2[k4 * 4 + e] * wv[e];
        }
    } else {
        for (int k8 = 0; k8 < 32; k8++) {
            s16x8 wv = *(const s16x8*)(mw2 + j * 256 + k8 * 8);
#pragma unroll
            for (int e = 0; e < 8; e++) a2 += h2[k8 * 8 + e] * bs2f(wv[e]);
        }
    }
    if (f32in) outf[b * 256 + j] = a2;
    else       out[b * 256 + j] = f2bu(a2);
}

// ---------------------------------------------------------------------------
extern "C" void kernel_launch(void* const* d_in, const int* in_sizes, int n_in,
                              void* d_out, int out_size, void* d_ws, size_t ws_size,
                              hipStream_t stream)
{
    const u16 *q16 = (const u16*)d_in[0], *k16 = (const u16*)d_in[1], *v16 = (const u16*)d_in[2];
    const float *qf = (const float*)d_in[0], *kf = (const float*)d_in[1], *vf = (const float*)d_in[2];

    const size_t TEN = 33554432ull;          // one [65536,256] bf16 tensor
    const size_t WBF_OFF = 2097152ull;       // bf16 weights at 2 MB
    const size_t BUF_OFF = 5242880ull;       // big buffers at 5 MB
    if (ws_size < BUF_OFF + 5 * TEN) return; // 165 MB

    char* ws = (char*)d_ws;
    int*   dflag = (int*)ws;
    float* fb    = (float*)ws;
    float* sums  = fb + 256;                 // 8 arrays x [2*NC][256] = 64K floats
    float* xcat  = sums + 8 * 2 * NC * 256;  // 32 x 1024
    u16*   wbf   = (u16*)(ws + WBF_OFF);     // 5 x [4,256,256] bf16
    u16* buf[5];
    for (int i = 0; i < 5; i++) buf[i] = (u16*)(ws + BUF_OFF + (size_t)i * TEN);

    // per-head buffer rotation (liveness-checked)
    const int qsrc[4] = {-1, 0, 3, 1}, qdst[4] = {0, 3, 1, 4};
    const int ksrc[4] = {-1, 1, 4, 2}, kdst[4] = {1, 4, 2, 0};
    const int vsrc[4] = {-1, 2, 0, 3}, vdst[4] = {2, 0, 3, 1};
    const int x1i[4]  = {3, 1, 4, 2},  lgi[4]  = {4, 2, 0, 3};

    detect_k<<<dim3(1), dim3(256), 0, stream>>>((const unsigned int*)d_in[0], dflag);
    hipMemsetAsync(sums, 0, 8 * 2 * NC * 256 * sizeof(float), stream);
    // slots: 0 wq, 1 wk, 2 wv, 3 wl1, 4 wl2
    wconv_k<<<dim3(256, 5), dim3(256), 0, stream>>>(
        d_in[3], d_in[5], d_in[7], d_in[11], d_in[15], dflag, wbf);

    for (int h = 0; h < 4; h++) {
        const u16* qi = h ? (const u16*)buf[qsrc[h]] : q16;
        const u16* ki = h ? (const u16*)buf[ksrc[h]] : k16;
        const u16* vi = h ? (const u16*)buf[vsrc[h]] : v16;
        u16* qo = buf[qdst[h]];
        u16* ko = buf[kdst[h]];
        u16* vo = buf[vdst[h]];
        u16* x1b = buf[x1i[h]];
        u16* lgb = buf[lgi[h]];
        const u16* Wq  = wbf + (0 * 4 + h) * 65536;
        const u16* Wk  = wbf + (1 * 4 + h) * 65536;
        const u16* Wv  = wbf + (2 * 4 + h) * 65536;
        const u16* Wl1 = wbf + (3 * 4 + h) * 65536;
        const u16* Wl2 = wbf + (4 * 4 + h) * 65536;
        float* st1 = sums + (h * 2 + 0) * 2 * NC * 256;
        float* st2 = sums + (h * 2 + 1) * 2 * NC * 256;
        float* parts = (float*)x1b;   // x1b dead during softmax; 3 MB partials
        const int hoff = h * 256;

        if (h == 0)
            proj2_k<true><<<dim3(2048, 2), dim3(256), 0, stream>>>(
                q16, qf, Wq, d_in[4], qo, v16, vf, Wv, d_in[8], vo, hoff, dflag);
        else
            proj2_k<false><<<dim3(2048, 2), dim3(256), 0, stream>>>(
                qi, nullptr, Wq, d_in[4], qo, vi, nullptr, Wv, d_in[8], vo, hoff, dflag);

        if (h == 0)
            gemm_k<0, true, 1><<<dim3(2048), dim3(256), 0, stream>>>(
                k16, kf, nullptr, qo, Wk, d_in[6], d_in[6], d_in[6], hoff,
                nullptr, st1, dflag, ko);
        else
            gemm_k<0, false, 1><<<dim3(2048), dim3(256), 0, stream>>>(
                ki, nullptr, nullptr, qo, Wk, d_in[6], d_in[6], d_in[6], hoff,
                nullptr, st1, dflag, ko);

        gemm_k<1, false, 2><<<dim3(2048), dim3(256), 0, stream>>>(
            ko, nullptr, qo, nullptr, Wl1, d_in[12], d_in[9], d_in[10], hoff,
            st1, st2, dflag, x1b);

        gemm_k<2, false, 0><<<dim3(2048), dim3(256), 0, stream>>>(
            x1b, nullptr, nullptr, nullptr, Wl2, d_in[16], d_in[13], d_in[14], hoff,
            st2, nullptr, dflag, lgb);

        softmax_chunk_k<<<dim3(32, 32), dim3(256), 0, stream>>>(
            lgb, vo, parts, parts + 262144, parts + 524288);
        softmax_merge_k<<<dim3(32), dim3(256), 0, stream>>>(
            parts, parts + 262144, parts + 524288, xcat, h);
    }
    mlp_k<<<dim3(32), dim3(256), 0, stream>>>(
        xcat,
        (const u16*)d_in[17], (const float*)d_in[17],
        (const u16*)d_in[18], (const float*)d_in[18],
        (const u16*)d_in[19], (const float*)d_in[19],
        (const u16*)d_in[20], (const float*)d_in[20],
        (const u16*)d_in[21], (const float*)d_in[21],
        (const u16*)d_in[22], (const float*)d_in[22],
        dflag, (u16*)d_out, (float*)d_out);
}